// Round 5
// baseline (508.566 us; speedup 1.0000x reference)
//
#include <hip/hip_runtime.h>
#include <stdint.h>

typedef __attribute__((ext_vector_type(8))) __bf16 bf16x8;
typedef __attribute__((ext_vector_type(4))) float f32x4;
typedef __attribute__((ext_vector_type(4))) unsigned int uint4v;

__device__ __forceinline__ float bf2f(unsigned short u){
  unsigned int x = ((unsigned int)u) << 16;
  return __builtin_bit_cast(float, x);
}
__device__ __forceinline__ unsigned short f2bf(float f){
  unsigned int x = __builtin_bit_cast(unsigned int, f);
  x += 0x7FFFu + ((x >> 16) & 1u);
  return (unsigned short)(x >> 16);
}

// async global->LDS, 16B per lane; LDS dest must be wave-uniform base + lane*16
__device__ __forceinline__ void async_copy16(const void* gsrc, void* ldsdst){
  auto g = reinterpret_cast<__attribute__((address_space(1))) unsigned int*>(
      reinterpret_cast<uintptr_t>(gsrc));
  auto l = reinterpret_cast<__attribute__((address_space(3))) unsigned int*>(
      reinterpret_cast<uintptr_t>(ldsdst));
  __builtin_amdgcn_global_load_lds(g, l, 16, 0, 0);
}

#define OUT_F32 0
#define OUT_BF16 1
#define OUT_SPLIT3 2
#define OUT_FLAG 3
#define OUT_PART 4
#define OUT_PARTH 5
#define BIAS_NONE 0
#define BIAS_ROW 1
#define BIAS_COL 2

// C(MxN) = A(MxK) * Bt(NxK)^T ; M,N multiples of 128, kchunk multiple of 32.
// blockIdx.z selects K-slice; OUT_PART(f32)/OUT_PARTH(bf16) write partials at
// z*zStride. A, Bt bf16 K-contiguous. 128x128 tile, 4 waves, 16x16x32 MFMA.
// LDS: row r at byte r*64; 16B-chunk p of row r holds k-chunk (p ^ ((r>>1)&3)).
// Staging via global_load_lds: wave w stages rows [32w,32w+32); lane i writes
// LDS linear offset wavebase + i*16 (wave-uniform base requirement).
template<int OM, int BM>
__global__ __launch_bounds__(256)
void gemm_bt(const unsigned short* __restrict__ A, int lda,
             const unsigned short* __restrict__ Bt, int ldb,
             int kchunk, void* __restrict__ Out, int ldo,
             const float* __restrict__ bias,
             int dupOff, int loOff,
             const unsigned int* __restrict__ flagPtr, size_t outOff,
             size_t zStride)
{
  __shared__ uint4v AsmBuf[512];
  __shared__ uint4v BsmBuf[512];
  char* Asm = (char*)AsmBuf;
  char* Bsm = (char*)BsmBuf;

  const unsigned int fl = (OM == OUT_FLAG) ? flagPtr[0] : 0u;

  const int tid  = threadIdx.x;
  const int lane = tid & 63;
  const int wave = tid >> 6;
  const int wy = wave >> 1, wx = wave & 1;
  const int lm = lane & 15, quad = lane >> 4;
  const int tileM = blockIdx.y * 128;
  const int tileN = blockIdx.x * 128;
  const int z = blockIdx.z;

  A  += (size_t)z * kchunk;
  Bt += (size_t)z * kchunk;

  // wave w stages rows [32w, 32w+32); lane i -> row 32w+(i>>2), phys chunk i&3
  const int r0 = wave*32 + (lane >> 2);
  const int r1 = r0 + 16;
  const int c  = lane & 3;
  const size_t gA0 = (size_t)(tileM + r0)*lda + ((c ^ ((r0 >> 1) & 3)) << 3);
  const size_t gA1 = (size_t)(tileM + r1)*lda + ((c ^ ((r1 >> 1) & 3)) << 3);
  const size_t gB0 = (size_t)(tileN + r0)*ldb + ((c ^ ((r0 >> 1) & 3)) << 3);
  const size_t gB1 = (size_t)(tileN + r1)*ldb + ((c ^ ((r1 >> 1) & 3)) << 3);
  char* AsmD0 = Asm + wave*2048;
  char* AsmD1 = Asm + wave*2048 + 1024;
  char* BsmD0 = Bsm + wave*2048;
  char* BsmD1 = Bsm + wave*2048 + 1024;

  int aOff[4], bOff[4];
#pragma unroll
  for (int t = 0; t < 4; ++t){
    int ra = wy*64 + t*16 + lm;
    aOff[t] = ra*64 + ((quad ^ ((ra >> 1) & 3)) << 4);
    int rb = wx*64 + t*16 + lm;
    bOff[t] = rb*64 + ((quad ^ ((rb >> 1) & 3)) << 4);
  }

  f32x4 acc[4][4] = {};

  const int ksteps = kchunk >> 5;
  for (int kt = 0; kt < ksteps; ++kt){
    const unsigned short* Ak = A + kt*32;
    const unsigned short* Bk = Bt + kt*32;
    async_copy16(Ak + gA0, AsmD0);
    async_copy16(Ak + gA1, AsmD1);
    async_copy16(Bk + gB0, BsmD0);
    async_copy16(Bk + gB1, BsmD1);
    __syncthreads();   // drains vmcnt (async LDS writes) + barrier
    bf16x8 af[4], bfr[4];
#pragma unroll
    for (int t = 0; t < 4; ++t){
      af[t]  = __builtin_bit_cast(bf16x8, *(const uint4v*)(Asm + aOff[t]));
      bfr[t] = __builtin_bit_cast(bf16x8, *(const uint4v*)(Bsm + bOff[t]));
    }
#pragma unroll
    for (int tm = 0; tm < 4; ++tm)
#pragma unroll
      for (int tn = 0; tn < 4; ++tn)
        acc[tm][tn] = __builtin_amdgcn_mfma_f32_16x16x32_bf16(af[tm], bfr[tn], acc[tm][tn], 0, 0, 0);
    __syncthreads();   // all waves' ds_reads done before next stage overwrites
  }

  // D row = quad*4 + reg, col = lane&15
#pragma unroll
  for (int tm = 0; tm < 4; ++tm){
    const int rowb = tileM + wy*64 + tm*16 + quad*4;
#pragma unroll
    for (int tn = 0; tn < 4; ++tn){
      const int col = tileN + wx*64 + tn*16 + lm;
      float bcv = 0.f;
      if (BM == BIAS_COL) bcv = bias[col];
#pragma unroll
      for (int r = 0; r < 4; ++r){
        float v = acc[tm][tn][r];
        const int row = rowb + r;
        if (BM == BIAS_ROW) v += bias[row];
        if (BM == BIAS_COL) v += bcv;
        const size_t idx = (size_t)row*ldo + col;
        if (OM == OUT_F32){
          ((float*)Out)[idx] = v;
        } else if (OM == OUT_BF16){
          ((unsigned short*)Out)[idx] = f2bf(v);
        } else if (OM == OUT_SPLIT3){
          unsigned short hi = f2bf(v);
          unsigned short lo = f2bf(v - bf2f(hi));
          unsigned short* O = (unsigned short*)Out;
          O[idx] = hi; O[idx + dupOff] = hi; O[idx + loOff] = lo;
        } else if (OM == OUT_PART){
          ((float*)Out)[(size_t)z*zStride + idx] = v;
        } else if (OM == OUT_PARTH){
          ((unsigned short*)Out)[(size_t)z*zStride + idx] = f2bf(v);
        } else { // OUT_FLAG
          if (fl) ((float*)Out)[outOff + idx] = v;
          else    ((unsigned short*)Out)[outOff + idx] = f2bf(v);
        }
      }
    }
  }
}

// sum S partial slices [S][M][256] -> epilogue. block = row, thread = col.
// HALFP: partials are bf16, else f32.
template<int S, int OM, bool HALFP>
__global__ __launch_bounds__(256)
void reduce_part(const void* __restrict__ part, size_t zStride,
                 const float* __restrict__ bias,
                 unsigned short* __restrict__ Out, int ldo,
                 int dupOff, int loOff)
{
  const int l = blockIdx.x, col = threadIdx.x;
  const size_t i0 = (size_t)l*256 + col;
  float v = 0.f;
#pragma unroll
  for (int s = 0; s < S; ++s){
    if (HALFP) v += bf2f(((const unsigned short*)part)[(size_t)s*zStride + i0]);
    else       v += ((const float*)part)[(size_t)s*zStride + i0];
  }
  const size_t o = (size_t)l*ldo + col;
  if (OM == OUT_SPLIT3){
    v += bias[col];
    unsigned short hi = f2bf(v);
    unsigned short lo = f2bf(v - bf2f(hi));
    Out[o] = hi; Out[o + dupOff] = hi; Out[o + loOff] = lo;
  } else {
    Out[o] = f2bf(v);
  }
}

// dtype vote + scalar/bias canonicalization (f32 canon)
__global__ __launch_bounds__(256)
void detect_prep(const void* __restrict__ content,
                 const void* tb, const void* pb, const void* gb, const void* wb,
                 const void* sc,
                 unsigned int* __restrict__ flag, float* __restrict__ scale_c,
                 float* tb_c, float* pb_c, float* gb_c, float* wb_c)
{
  __shared__ int cnt;
  __shared__ unsigned int flg;
  const int tid = threadIdx.x;
  if (tid == 0) cnt = 0;
  __syncthreads();
  unsigned int w = ((const unsigned int*)content)[tid];
  int e = (w >> 23) & 0xFF;
  if (e >= 0x70 && e <= 0x8F) atomicAdd(&cnt, 1);
  __syncthreads();
  if (tid == 0){ flg = (cnt >= 128) ? 1u : 0u; flag[0] = flg; }
  __syncthreads();
  const unsigned int f = flg;
  auto rd = [&](const void* p, int i)->float{
    return f ? ((const float*)p)[i] : bf2f(((const unsigned short*)p)[i]);
  };
  if (tid < 9) scale_c[tid] = rd(sc, tid);
  tb_c[tid] = rd(tb, tid);
  pb_c[tid] = rd(pb, tid);
  gb_c[tid] = rd(gb, tid);
  wb_c[tid] = rd(wb, tid);
  wb_c[tid + 256] = rd(wb, tid + 256);
}

// canonicalize weights: theta/phi -> wdup rows [whi(512)|wlo(512)|whi(512)],
// g_w -> gwc bf16, W_w -> wwc bf16
__global__ __launch_bounds__(256)
void conv_weights(const void* tw, const void* pw, const void* gw, const void* www,
                  const unsigned int* __restrict__ flagPtr,
                  unsigned short* __restrict__ wdup,
                  unsigned short* __restrict__ gwc,
                  unsigned short* __restrict__ wwc)
{
  const unsigned int fl = flagPtr[0];
  const int sec = blockIdx.y;
  const int idx = blockIdx.x*256 + threadIdx.x;
  auto rd = [&](const void* p, int i)->float{
    return fl ? ((const float*)p)[i] : bf2f(((const unsigned short*)p)[i]);
  };
  if (sec < 2){
    const void* w = sec ? pw : tw;
    const int o = idx >> 9, c = idx & 511;
    float v = rd(w, o*512 + c);
    unsigned short hi = f2bf(v);
    unsigned short lo = f2bf(v - bf2f(hi));
    unsigned short* base = wdup + (size_t)sec*256*1536 + o*1536;
    base[c] = hi; base[512 + c] = lo; base[1024 + c] = hi;
  } else if (sec == 2){
    const int o = idx >> 9, c = idx & 511;
    gwc[o*512 + c] = f2bf(rd(gw, o*512 + c));
  } else {
    const int o = idx >> 8, c = idx & 255;
    wwc[o*256 + c] = f2bf(rd(www, o*256 + c));
  }
}

// per-(b,c) mean / invstd over 4096 spatial elems (unbiased var)
__global__ __launch_bounds__(256)
void stats_kernel(const void* __restrict__ X, const unsigned int* __restrict__ flagPtr,
                  float* __restrict__ stats)
{
  const unsigned int fl = flagPtr[0];
  const int bc = blockIdx.x;
  const int tid = threadIdx.x;
  float s = 0.f, q = 0.f;
  if (fl){
    const f32x4* row = (const f32x4*)((const float*)X + (size_t)bc*4096);
#pragma unroll
    for (int i = 0; i < 4; ++i){
      f32x4 v = row[tid + i*256];
#pragma unroll
      for (int j = 0; j < 4; ++j){ s += v[j]; q += v[j]*v[j]; }
    }
  } else {
    const uint4v* row = (const uint4v*)((const unsigned short*)X + (size_t)bc*4096);
#pragma unroll
    for (int i = 0; i < 2; ++i){
      uint4v u = row[tid + i*256];
#pragma unroll
      for (int j = 0; j < 4; ++j){
        float a = bf2f((unsigned short)(u[j] & 0xffffu));
        float b = bf2f((unsigned short)(u[j] >> 16));
        s += a + b; q += a*a + b*b;
      }
    }
  }
#pragma unroll
  for (int off = 32; off > 0; off >>= 1){
    s += __shfl_down(s, off);
    q += __shfl_down(q, off);
  }
  __shared__ float rs[4], rq[4];
  if ((tid & 63) == 0){ rs[tid >> 6] = s; rq[tid >> 6] = q; }
  __syncthreads();
  if (tid == 0){
    s = rs[0] + rs[1] + rs[2] + rs[3];
    q = rq[0] + rq[1] + rq[2] + rq[3];
    float mean = s * (1.0f/4096.0f);
    float var  = (q - 4096.0f*mean*mean) * (1.0f/4095.0f);
    stats[bc*2 + 0] = mean;
    stats[bc*2 + 1] = 1.0f / sqrtf(var + 1e-5f);
  }
}

// (c,l) -> (l,c) transpose for batch b.
// SPLIT: normalize, write rows [xhi(512)|xhi(512)|xlo(512)] (ldo=1536)
// else: plain bf16 (ldo=512)
template<bool SPLIT>
__global__ __launch_bounds__(256)
void norm_transpose(const void* __restrict__ X, const float* __restrict__ stats,
                    unsigned short* __restrict__ Out,
                    const unsigned int* __restrict__ flagPtr, int b)
{
  __shared__ float tile[64][65];
  const unsigned int fl = flagPtr[0];
  const int l0 = blockIdx.x * 64;
  const int c0 = blockIdx.y * 64;
  const int tid = threadIdx.x;
  const int tx = tid & 63, ty = tid >> 6;

#pragma unroll
  for (int p = 0; p < 16; ++p){
    const int cc = ty + p*4;
    const size_t src = ((size_t)b*512 + c0 + cc)*4096 + l0 + tx;
    tile[cc][tx] = fl ? ((const float*)X)[src]
                      : bf2f(((const unsigned short*)X)[src]);
  }
  __syncthreads();
  float mean = 0.f, inv = 1.f;
  if (SPLIT){
    mean = stats[(b*512 + c0 + tx)*2 + 0];
    inv  = stats[(b*512 + c0 + tx)*2 + 1];
  }
#pragma unroll
  for (int p = 0; p < 16; ++p){
    const int lj = ty + p*4;
    if (SPLIT){
      const float v = (tile[tx][lj] - mean) * inv;
      const size_t o = (size_t)(l0 + lj)*1536 + c0 + tx;
      const unsigned short hi = f2bf(v);
      Out[o] = hi;
      Out[o + 512] = hi;
      Out[o + 1024] = f2bf(v - bf2f(hi));
    } else {
      const size_t o = (size_t)(l0 + lj)*512 + c0 + tx;
      Out[o] = f2bf(tile[tx][lj]);
    }
  }
}

// f[l,m] = sum_{di,dj} s^2 * G[refl_l, refl_m]; rowwise softmax; write P bf16
__global__ __launch_bounds__(256)
void softmax_rows(const float* __restrict__ G, const float* __restrict__ scale_c,
                  unsigned short* __restrict__ P)
{
  const int l = blockIdx.x;
  const int yy = l >> 6, xx = l & 63;
  const int tid = threadIdx.x;

  float s2[9];
  const float* rowp[9];
#pragma unroll
  for (int di = 0; di < 3; ++di){
    int ry = yy + di - 1; ry = ry < 0 ? 1 : (ry > 63 ? 62 : ry);
#pragma unroll
    for (int dj = 0; dj < 3; ++dj){
      int rx = xx + dj - 1; rx = rx < 0 ? 1 : (rx > 63 ? 62 : rx);
      const int k = di*3 + dj;
      const float s = scale_c[k];
      s2[k] = s*s;
      rowp[k] = G + (size_t)(ry*64 + rx)*4096;
    }
  }

  float fv[16];
  float mx = -3.0e38f;
#pragma unroll
  for (int i = 0; i < 16; ++i){
    const int m = tid + i*256;
    const int my = m >> 6, mxo = m & 63;
    int cy[3], cx[3];
#pragma unroll
    for (int d = 0; d < 3; ++d){
      int t0 = my + d - 1;  cy[d] = (t0 < 0 ? 1 : (t0 > 63 ? 62 : t0))*64;
      int t1 = mxo + d - 1; cx[d] = (t1 < 0 ? 1 : (t1 > 63 ? 62 : t1));
    }
    float v = 0.f;
#pragma unroll
    for (int di = 0; di < 3; ++di)
#pragma unroll
      for (int dj = 0; dj < 3; ++dj)
        v = fmaf(s2[di*3+dj], rowp[di*3+dj][cy[di] + cx[dj]], v);
    fv[i] = v;
    mx = fmaxf(mx, v);
  }

  __shared__ float redA[4], redB[4];
#pragma unroll
  for (int off = 32; off > 0; off >>= 1) mx = fmaxf(mx, __shfl_down(mx, off));
  if ((tid & 63) == 0) redA[tid >> 6] = mx;
  __syncthreads();
  mx = fmaxf(fmaxf(redA[0], redA[1]), fmaxf(redA[2], redA[3]));

  float sum = 0.f;
#pragma unroll
  for (int i = 0; i < 16; ++i){ fv[i] = __expf(fv[i] - mx); sum += fv[i]; }
#pragma unroll
  for (int off = 32; off > 0; off >>= 1) sum += __shfl_down(sum, off);
  if ((tid & 63) == 0) redB[tid >> 6] = sum;
  __syncthreads();
  sum = redB[0] + redB[1] + redB[2] + redB[3];
  const float inv = 1.0f / sum;

  unsigned short* Prow = P + (size_t)l*4096;
#pragma unroll
  for (int i = 0; i < 16; ++i) Prow[tid + i*256] = f2bf(fv[i]*inv);
}

extern "C" void kernel_launch(void* const* d_in, const int* in_sizes, int n_in,
                              void* d_out, int out_size, void* d_ws, size_t ws_size,
                              hipStream_t stream)
{
  const void* content = d_in[0];
  const void* style   = d_in[1];
  const void* fusion  = d_in[2];
  const void* theta_w = d_in[3];
  const void* theta_b = d_in[4];
  const void* phi_w   = d_in[5];
  const void* phi_b   = d_in[6];
  const void* g_w     = d_in[7];
  const void* g_b     = d_in[8];
  const void* W_w     = d_in[9];
  const void* W_b     = d_in[10];
  const void* scale   = d_in[11];

  char* ws = (char*)d_ws;
  size_t off = 0;
  auto take = [&](size_t bytes)->char*{
    char* p = ws + off; off += (bytes + 255) & ~(size_t)255; return p;
  };

  unsigned int* flag  = (unsigned int*)take(256);
  float* scale_c      = (float*)take(256);
  float* tb_c         = (float*)take(1024);
  float* pb_c         = (float*)take(1024);
  float* gb_c         = (float*)take(1024);
  float* wb_c         = (float*)take(2048);
  float* statsC       = (float*)take(1024ull*2*4);
  float* statsS       = (float*)take(1024ull*2*4);
  unsigned short* wdup = (unsigned short*)take(2ull*256*1536*2); // theta|phi [hi|lo|hi]
  unsigned short* gwc  = (unsigned short*)take(256ull*512*2);
  unsigned short* wwc  = (unsigned short*)take(512ull*256*2);
  unsigned short* th   = (unsigned short*)take(4096ull*768*2);   // per-batch [hi|hi|lo]
  unsigned short* ph   = (unsigned short*)take(4096ull*768*2);   // per-batch [hi|lo|hi]
  unsigned short* gs   = (unsigned short*)take(256ull*4096*2);   // per-batch [o][m]
  unsigned short* yb   = (unsigned short*)take(4096ull*256*2);   // per-batch [l][o]
  float* G             = (float*)take(4096ull*4096*4);           // per-batch
  char* unionB         = take(4096ull*4096*2);                   // 32MB union
  unsigned short* xn   = (unsigned short*)unionB;
  unsigned short* sn   = (unsigned short*)(unionB + 4096ull*1536*2);
  unsigned short* fst  = (unsigned short*)(unionB + 2ull*4096*1536*2);
  unsigned short* P    = (unsigned short*)unionB;                // after xn/sn/fst dead
  float* partF         = G;                  // f32 partials overlay dead G
  unsigned short* partH = (unsigned short*)G; // bf16 partials overlay dead G
  const size_t zS = 4096ull*256;

  detect_prep<<<1, 256, 0, stream>>>(content, theta_b, phi_b, g_b, W_b, scale,
                                     flag, scale_c, tb_c, pb_c, gb_c, wb_c);
  conv_weights<<<dim3(512,4), 256, 0, stream>>>(theta_w, phi_w, g_w, W_w, flag,
                                                wdup, gwc, wwc);
  stats_kernel<<<1024, 256, 0, stream>>>(content, flag, statsC);
  stats_kernel<<<1024, 256, 0, stream>>>(style,   flag, statsS);

  for (int b = 0; b < 2; ++b){
    dim3 ntg(64, 8, 1);
    norm_transpose<true ><<<ntg, 256, 0, stream>>>(content, statsC, xn, flag, b);
    norm_transpose<true ><<<ntg, 256, 0, stream>>>(style,   statsS, sn, flag, b);
    norm_transpose<false><<<ntg, 256, 0, stream>>>(fusion,  nullptr, fst, flag, b);

    // theta: (4096x256) = xn(4096x1536)*wdup_t(256x1536)^T, split-K 4x384 (f32 partials)
    gemm_bt<OUT_PART, BIAS_NONE><<<dim3(2,32,4), 256, 0, stream>>>(
        xn, 1536, wdup, 1536, 384, partF, 256, nullptr, 0, 0, nullptr, 0, zS);
    reduce_part<4, OUT_SPLIT3, false><<<4096, 256, 0, stream>>>(
        partF, zS, tb_c, th, 768, 256, 512);
    // phi -> ph [hi|lo|hi]
    gemm_bt<OUT_PART, BIAS_NONE><<<dim3(2,32,4), 256, 0, stream>>>(
        sn, 1536, wdup + 256*1536, 1536, 384, partF, 256, nullptr, 0, 0, nullptr, 0, zS);
    reduce_part<4, OUT_SPLIT3, false><<<4096, 256, 0, stream>>>(
        partF, zS, pb_c, ph, 768, 512, 256);
    // g: (256x4096) = gwc(256x512) * fst(4096x512)^T
    gemm_bt<OUT_BF16, BIAS_ROW><<<dim3(32,2), 256, 0, stream>>>(
        gwc, 512, fst, 512, 512, gs, 4096, gb_c, 0, 0, nullptr, 0, 0);
    // G = th * ph^T (f32), K=768 compensated product
    gemm_bt<OUT_F32, BIAS_NONE><<<dim3(32,32), 256, 0, stream>>>(
        th, 768, ph, 768, 768, G, 4096, nullptr, 0, 0, nullptr, 0, 0);
    // f-assembly + rowwise softmax -> P (bf16); P overlays dead xn/sn/fst
    softmax_rows<<<4096, 256, 0, stream>>>(G, scale_c, P);
    // y = P * gs^T : (4096x256), split-K 8x512, bf16 partials (overlay dead G)
    gemm_bt<OUT_PARTH, BIAS_NONE><<<dim3(2,32,8), 256, 0, stream>>>(
        P, 4096, gs, 4096, 512, partH, 256, nullptr, 0, 0, nullptr, 0, zS);
    reduce_part<8, OUT_BF16, true><<<4096, 256, 0, stream>>>(
        partH, zS, nullptr, yb, 256, 0, 0);
    // out = wwc(512x256) * yb(4096x256)^T + W_b ; dtype per flag
    gemm_bt<OUT_FLAG, BIAS_ROW><<<dim3(32,4), 256, 0, stream>>>(
        wwc, 256, yb, 256, 256, d_out, 4096, wb_c, 0, 0, flag,
        (size_t)b*512*4096, 0);
  }
}

// Round 6
// 494.642 us; speedup vs baseline: 1.0281x; 1.0281x over previous
//
#include <hip/hip_runtime.h>
#include <stdint.h>

typedef __attribute__((ext_vector_type(8))) __bf16 bf16x8;
typedef __attribute__((ext_vector_type(4))) float f32x4;
typedef __attribute__((ext_vector_type(4))) unsigned int uint4v;

__device__ __forceinline__ float bf2f(unsigned short u){
  unsigned int x = ((unsigned int)u) << 16;
  return __builtin_bit_cast(float, x);
}
__device__ __forceinline__ unsigned short f2bf(float f){
  unsigned int x = __builtin_bit_cast(unsigned int, f);
  x += 0x7FFFu + ((x >> 16) & 1u);
  return (unsigned short)(x >> 16);
}

#define OUT_F32 0
#define OUT_BF16 1
#define OUT_SPLIT3 2
#define OUT_FLAG 3
#define OUT_PART 4
#define OUT_PARTH 5
#define BIAS_NONE 0
#define BIAS_ROW 1
#define BIAS_COL 2

// C(MxN) = A(MxK) * Bt(NxK)^T ; M,N multiples of 128, kchunk multiple of 32.
// blockIdx.z selects K-slice; OUT_PART(f32)/OUT_PARTH(bf16) write partials at
// z*zStride. A, Bt bf16 K-contiguous. 128x128 tile, 4 waves, 16x16x32 MFMA.
// Register staging (global->VGPR->LDS): compiler hoists next iter's global
// loads above the barrier => implicit prefetch. (async global_load_lds
// variant measured SLOWER here: R5 52us vs 45.5us.)
// LDS: row r at byte r*64; 16B-chunk p of row r holds k-chunk (p ^ ((r>>1)&3)).
template<int OM, int BM>
__global__ __launch_bounds__(256)
void gemm_bt(const unsigned short* __restrict__ A, int lda,
             const unsigned short* __restrict__ Bt, int ldb,
             int kchunk, void* __restrict__ Out, int ldo,
             const float* __restrict__ bias,
             int dupOff, int loOff,
             const unsigned int* __restrict__ flagPtr, size_t outOff,
             size_t zStride)
{
  __shared__ uint4v AsmBuf[512];
  __shared__ uint4v BsmBuf[512];
  char* Asm = (char*)AsmBuf;
  char* Bsm = (char*)BsmBuf;

  const unsigned int fl = (OM == OUT_FLAG) ? flagPtr[0] : 0u;

  const int tid  = threadIdx.x;
  const int lane = tid & 63;
  const int wave = tid >> 6;
  const int wy = wave >> 1, wx = wave & 1;
  const int lm = lane & 15, quad = lane >> 4;
  const int tileM = blockIdx.y * 128;
  const int tileN = blockIdx.x * 128;
  const int z = blockIdx.z;

  A  += (size_t)z * kchunk;
  Bt += (size_t)z * kchunk;

  const int sr0 = tid >> 2, sc0 = tid & 3;
  const int sr1 = sr0 + 64;
  const size_t gA0 = (size_t)(tileM + sr0)*lda + ((sc0 ^ ((sr0 >> 1) & 3)) << 3);
  const size_t gA1 = (size_t)(tileM + sr1)*lda + ((sc0 ^ ((sr1 >> 1) & 3)) << 3);
  const size_t gB0 = (size_t)(tileN + sr0)*ldb + ((sc0 ^ ((sr0 >> 1) & 3)) << 3);
  const size_t gB1 = (size_t)(tileN + sr1)*ldb + ((sc0 ^ ((sr1 >> 1) & 3)) << 3);
  const int lOff0 = sr0*64 + sc0*16;
  const int lOff1 = sr1*64 + sc0*16;

  int aOff[4], bOff[4];
#pragma unroll
  for (int t = 0; t < 4; ++t){
    int ra = wy*64 + t*16 + lm;
    aOff[t] = ra*64 + ((quad ^ ((ra >> 1) & 3)) << 4);
    int rb = wx*64 + t*16 + lm;
    bOff[t] = rb*64 + ((quad ^ ((rb >> 1) & 3)) << 4);
  }

  f32x4 acc[4][4] = {};

  const int ksteps = kchunk >> 5;
  for (int kt = 0; kt < ksteps; ++kt){
    const unsigned short* Ak = A + kt*32;
    const unsigned short* Bk = Bt + kt*32;
    uint4v a0v = *(const uint4v*)(Ak + gA0);
    uint4v a1v = *(const uint4v*)(Ak + gA1);
    uint4v b0v = *(const uint4v*)(Bk + gB0);
    uint4v b1v = *(const uint4v*)(Bk + gB1);
    __syncthreads();
    *(uint4v*)(Asm + lOff0) = a0v;
    *(uint4v*)(Asm + lOff1) = a1v;
    *(uint4v*)(Bsm + lOff0) = b0v;
    *(uint4v*)(Bsm + lOff1) = b1v;
    __syncthreads();
    bf16x8 af[4], bfr[4];
#pragma unroll
    for (int t = 0; t < 4; ++t){
      af[t]  = __builtin_bit_cast(bf16x8, *(const uint4v*)(Asm + aOff[t]));
      bfr[t] = __builtin_bit_cast(bf16x8, *(const uint4v*)(Bsm + bOff[t]));
    }
#pragma unroll
    for (int tm = 0; tm < 4; ++tm)
#pragma unroll
      for (int tn = 0; tn < 4; ++tn)
        acc[tm][tn] = __builtin_amdgcn_mfma_f32_16x16x32_bf16(af[tm], bfr[tn], acc[tm][tn], 0, 0, 0);
  }

  // D row = quad*4 + reg, col = lane&15
#pragma unroll
  for (int tm = 0; tm < 4; ++tm){
    const int rowb = tileM + wy*64 + tm*16 + quad*4;
#pragma unroll
    for (int tn = 0; tn < 4; ++tn){
      const int col = tileN + wx*64 + tn*16 + lm;
      float bcv = 0.f;
      if (BM == BIAS_COL) bcv = bias[col];
#pragma unroll
      for (int r = 0; r < 4; ++r){
        float v = acc[tm][tn][r];
        const int row = rowb + r;
        if (BM == BIAS_ROW) v += bias[row];
        if (BM == BIAS_COL) v += bcv;
        const size_t idx = (size_t)row*ldo + col;
        if (OM == OUT_F32){
          ((float*)Out)[idx] = v;
        } else if (OM == OUT_BF16){
          ((unsigned short*)Out)[idx] = f2bf(v);
        } else if (OM == OUT_SPLIT3){
          unsigned short hi = f2bf(v);
          unsigned short lo = f2bf(v - bf2f(hi));
          unsigned short* O = (unsigned short*)Out;
          O[idx] = hi; O[idx + dupOff] = hi; O[idx + loOff] = lo;
        } else if (OM == OUT_PART){
          ((float*)Out)[(size_t)z*zStride + idx] = v;
        } else if (OM == OUT_PARTH){
          ((unsigned short*)Out)[(size_t)z*zStride + idx] = f2bf(v);
        } else { // OUT_FLAG
          if (fl) ((float*)Out)[outOff + idx] = v;
          else    ((unsigned short*)Out)[outOff + idx] = f2bf(v);
        }
      }
    }
  }
}

// sum S partial slices (flat [S][rows*cols]) -> epilogue.
// CSH = log2(cols). HALFP: bf16 partials. i = bid*256+tid; row=i>>CSH, col=i&mask.
template<int S, int OM, int BM, int CSH, bool HALFP>
__global__ __launch_bounds__(256)
void reduce_part(const void* __restrict__ part, size_t zStride,
                 const float* __restrict__ bias,
                 void* __restrict__ Out, int ldo,
                 int dupOff, int loOff,
                 const unsigned int* __restrict__ flagPtr, size_t outOff)
{
  const size_t i = (size_t)blockIdx.x*256 + threadIdx.x;
  const int row = (int)(i >> CSH);
  const int col = (int)(i & ((1u << CSH) - 1u));
  float v = 0.f;
#pragma unroll
  for (int s = 0; s < S; ++s){
    if (HALFP) v += bf2f(((const unsigned short*)part)[(size_t)s*zStride + i]);
    else       v += ((const float*)part)[(size_t)s*zStride + i];
  }
  if (BM == BIAS_ROW) v += bias[row];
  if (BM == BIAS_COL) v += bias[col];
  const size_t o = (size_t)row*ldo + col;
  if (OM == OUT_SPLIT3){
    unsigned short hi = f2bf(v);
    unsigned short lo = f2bf(v - bf2f(hi));
    unsigned short* O = (unsigned short*)Out;
    O[o] = hi; O[o + dupOff] = hi; O[o + loOff] = lo;
  } else if (OM == OUT_BF16){
    ((unsigned short*)Out)[o] = f2bf(v);
  } else { // OUT_FLAG
    if (flagPtr[0]) ((float*)Out)[outOff + o] = v;
    else            ((unsigned short*)Out)[outOff + o] = f2bf(v);
  }
}

// dtype vote + scalar/bias canonicalization (f32 canon)
__global__ __launch_bounds__(256)
void detect_prep(const void* __restrict__ content,
                 const void* tb, const void* pb, const void* gb, const void* wb,
                 const void* sc,
                 unsigned int* __restrict__ flag, float* __restrict__ scale_c,
                 float* tb_c, float* pb_c, float* gb_c, float* wb_c)
{
  __shared__ int cnt;
  __shared__ unsigned int flg;
  const int tid = threadIdx.x;
  if (tid == 0) cnt = 0;
  __syncthreads();
  unsigned int w = ((const unsigned int*)content)[tid];
  int e = (w >> 23) & 0xFF;
  if (e >= 0x70 && e <= 0x8F) atomicAdd(&cnt, 1);
  __syncthreads();
  if (tid == 0){ flg = (cnt >= 128) ? 1u : 0u; flag[0] = flg; }
  __syncthreads();
  const unsigned int f = flg;
  auto rd = [&](const void* p, int i)->float{
    return f ? ((const float*)p)[i] : bf2f(((const unsigned short*)p)[i]);
  };
  if (tid < 9) scale_c[tid] = rd(sc, tid);
  tb_c[tid] = rd(tb, tid);
  pb_c[tid] = rd(pb, tid);
  gb_c[tid] = rd(gb, tid);
  wb_c[tid] = rd(wb, tid);
  wb_c[tid + 256] = rd(wb, tid + 256);
}

// canonicalize weights: theta/phi -> wdup rows [whi(512)|wlo(512)|whi(512)],
// g_w -> gwc bf16, W_w -> wwc bf16
__global__ __launch_bounds__(256)
void conv_weights(const void* tw, const void* pw, const void* gw, const void* www,
                  const unsigned int* __restrict__ flagPtr,
                  unsigned short* __restrict__ wdup,
                  unsigned short* __restrict__ gwc,
                  unsigned short* __restrict__ wwc)
{
  const unsigned int fl = flagPtr[0];
  const int sec = blockIdx.y;
  const int idx = blockIdx.x*256 + threadIdx.x;
  auto rd = [&](const void* p, int i)->float{
    return fl ? ((const float*)p)[i] : bf2f(((const unsigned short*)p)[i]);
  };
  if (sec < 2){
    const void* w = sec ? pw : tw;
    const int o = idx >> 9, c = idx & 511;
    float v = rd(w, o*512 + c);
    unsigned short hi = f2bf(v);
    unsigned short lo = f2bf(v - bf2f(hi));
    unsigned short* base = wdup + (size_t)sec*256*1536 + o*1536;
    base[c] = hi; base[512 + c] = lo; base[1024 + c] = hi;
  } else if (sec == 2){
    const int o = idx >> 9, c = idx & 511;
    gwc[o*512 + c] = f2bf(rd(gw, o*512 + c));
  } else {
    const int o = idx >> 8, c = idx & 255;
    wwc[o*256 + c] = f2bf(rd(www, o*256 + c));
  }
}

// per-(b,c) mean / invstd over 4096 spatial elems (unbiased var)
__global__ __launch_bounds__(256)
void stats_kernel(const void* __restrict__ X, const unsigned int* __restrict__ flagPtr,
                  float* __restrict__ stats)
{
  const unsigned int fl = flagPtr[0];
  const int bc = blockIdx.x;
  const int tid = threadIdx.x;
  float s = 0.f, q = 0.f;
  if (fl){
    const f32x4* row = (const f32x4*)((const float*)X + (size_t)bc*4096);
#pragma unroll
    for (int i = 0; i < 4; ++i){
      f32x4 v = row[tid + i*256];
#pragma unroll
      for (int j = 0; j < 4; ++j){ s += v[j]; q += v[j]*v[j]; }
    }
  } else {
    const uint4v* row = (const uint4v*)((const unsigned short*)X + (size_t)bc*4096);
#pragma unroll
    for (int i = 0; i < 2; ++i){
      uint4v u = row[tid + i*256];
#pragma unroll
      for (int j = 0; j < 4; ++j){
        float a = bf2f((unsigned short)(u[j] & 0xffffu));
        float b = bf2f((unsigned short)(u[j] >> 16));
        s += a + b; q += a*a + b*b;
      }
    }
  }
#pragma unroll
  for (int off = 32; off > 0; off >>= 1){
    s += __shfl_down(s, off);
    q += __shfl_down(q, off);
  }
  __shared__ float rs[4], rq[4];
  if ((tid & 63) == 0){ rs[tid >> 6] = s; rq[tid >> 6] = q; }
  __syncthreads();
  if (tid == 0){
    s = rs[0] + rs[1] + rs[2] + rs[3];
    q = rq[0] + rq[1] + rq[2] + rq[3];
    float mean = s * (1.0f/4096.0f);
    float var  = (q - 4096.0f*mean*mean) * (1.0f/4095.0f);
    stats[bc*2 + 0] = mean;
    stats[bc*2 + 1] = 1.0f / sqrtf(var + 1e-5f);
  }
}

// (c,l) -> (l,c) transpose for batch b.
// SPLIT: normalize, write rows [xhi(512)|xhi(512)|xlo(512)] (ldo=1536)
// else: plain bf16 (ldo=512)
template<bool SPLIT>
__global__ __launch_bounds__(256)
void norm_transpose(const void* __restrict__ X, const float* __restrict__ stats,
                    unsigned short* __restrict__ Out,
                    const unsigned int* __restrict__ flagPtr, int b)
{
  __shared__ float tile[64][65];
  const unsigned int fl = flagPtr[0];
  const int l0 = blockIdx.x * 64;
  const int c0 = blockIdx.y * 64;
  const int tid = threadIdx.x;
  const int tx = tid & 63, ty = tid >> 6;

#pragma unroll
  for (int p = 0; p < 16; ++p){
    const int cc = ty + p*4;
    const size_t src = ((size_t)b*512 + c0 + cc)*4096 + l0 + tx;
    tile[cc][tx] = fl ? ((const float*)X)[src]
                      : bf2f(((const unsigned short*)X)[src]);
  }
  __syncthreads();
  float mean = 0.f, inv = 1.f;
  if (SPLIT){
    mean = stats[(b*512 + c0 + tx)*2 + 0];
    inv  = stats[(b*512 + c0 + tx)*2 + 1];
  }
#pragma unroll
  for (int p = 0; p < 16; ++p){
    const int lj = ty + p*4;
    if (SPLIT){
      const float v = (tile[tx][lj] - mean) * inv;
      const size_t o = (size_t)(l0 + lj)*1536 + c0 + tx;
      const unsigned short hi = f2bf(v);
      Out[o] = hi;
      Out[o + 512] = hi;
      Out[o + 1024] = f2bf(v - bf2f(hi));
    } else {
      const size_t o = (size_t)(l0 + lj)*512 + c0 + tx;
      Out[o] = f2bf(tile[tx][lj]);
    }
  }
}

// f[l,m] = sum_{di,dj} s^2 * G[refl_l, refl_m]; rowwise softmax; write P bf16
__global__ __launch_bounds__(256)
void softmax_rows(const float* __restrict__ G, const float* __restrict__ scale_c,
                  unsigned short* __restrict__ P)
{
  const int l = blockIdx.x;
  const int yy = l >> 6, xx = l & 63;
  const int tid = threadIdx.x;

  float s2[9];
  const float* rowp[9];
#pragma unroll
  for (int di = 0; di < 3; ++di){
    int ry = yy + di - 1; ry = ry < 0 ? 1 : (ry > 63 ? 62 : ry);
#pragma unroll
    for (int dj = 0; dj < 3; ++dj){
      int rx = xx + dj - 1; rx = rx < 0 ? 1 : (rx > 63 ? 62 : rx);
      const int k = di*3 + dj;
      const float s = scale_c[k];
      s2[k] = s*s;
      rowp[k] = G + (size_t)(ry*64 + rx)*4096;
    }
  }

  float fv[16];
  float mx = -3.0e38f;
#pragma unroll
  for (int i = 0; i < 16; ++i){
    const int m = tid + i*256;
    const int my = m >> 6, mxo = m & 63;
    int cy[3], cx[3];
#pragma unroll
    for (int d = 0; d < 3; ++d){
      int t0 = my + d - 1;  cy[d] = (t0 < 0 ? 1 : (t0 > 63 ? 62 : t0))*64;
      int t1 = mxo + d - 1; cx[d] = (t1 < 0 ? 1 : (t1 > 63 ? 62 : t1));
    }
    float v = 0.f;
#pragma unroll
    for (int di = 0; di < 3; ++di)
#pragma unroll
      for (int dj = 0; dj < 3; ++dj)
        v = fmaf(s2[di*3+dj], rowp[di*3+dj][cy[di] + cx[dj]], v);
    fv[i] = v;
    mx = fmaxf(mx, v);
  }

  __shared__ float redA[4], redB[4];
#pragma unroll
  for (int off = 32; off > 0; off >>= 1) mx = fmaxf(mx, __shfl_down(mx, off));
  if ((tid & 63) == 0) redA[tid >> 6] = mx;
  __syncthreads();
  mx = fmaxf(fmaxf(redA[0], redA[1]), fmaxf(redA[2], redA[3]));

  float sum = 0.f;
#pragma unroll
  for (int i = 0; i < 16; ++i){ fv[i] = __expf(fv[i] - mx); sum += fv[i]; }
#pragma unroll
  for (int off = 32; off > 0; off >>= 1) sum += __shfl_down(sum, off);
  if ((tid & 63) == 0) redB[tid >> 6] = sum;
  __syncthreads();
  sum = redB[0] + redB[1] + redB[2] + redB[3];
  const float inv = 1.0f / sum;

  unsigned short* Prow = P + (size_t)l*4096;
#pragma unroll
  for (int i = 0; i < 16; ++i) Prow[tid + i*256] = f2bf(fv[i]*inv);
}

extern "C" void kernel_launch(void* const* d_in, const int* in_sizes, int n_in,
                              void* d_out, int out_size, void* d_ws, size_t ws_size,
                              hipStream_t stream)
{
  const void* content = d_in[0];
  const void* style   = d_in[1];
  const void* fusion  = d_in[2];
  const void* theta_w = d_in[3];
  const void* theta_b = d_in[4];
  const void* phi_w   = d_in[5];
  const void* phi_b   = d_in[6];
  const void* g_w     = d_in[7];
  const void* g_b     = d_in[8];
  const void* W_w     = d_in[9];
  const void* W_b     = d_in[10];
  const void* scale   = d_in[11];

  char* ws = (char*)d_ws;
  size_t off = 0;
  auto take = [&](size_t bytes)->char*{
    char* p = ws + off; off += (bytes + 255) & ~(size_t)255; return p;
  };

  unsigned int* flag  = (unsigned int*)take(256);
  float* scale_c      = (float*)take(256);
  float* tb_c         = (float*)take(1024);
  float* pb_c         = (float*)take(1024);
  float* gb_c         = (float*)take(1024);
  float* wb_c         = (float*)take(2048);
  float* statsC       = (float*)take(1024ull*2*4);
  float* statsS       = (float*)take(1024ull*2*4);
  unsigned short* wdup = (unsigned short*)take(2ull*256*1536*2); // theta|phi [hi|lo|hi]
  unsigned short* gwc  = (unsigned short*)take(256ull*512*2);
  unsigned short* wwc  = (unsigned short*)take(512ull*256*2);
  unsigned short* th   = (unsigned short*)take(4096ull*768*2);   // per-batch [hi|hi|lo]
  unsigned short* ph   = (unsigned short*)take(4096ull*768*2);   // per-batch [hi|lo|hi]
  unsigned short* gs   = (unsigned short*)take(256ull*4096*2);   // per-batch [o][m]
  unsigned short* yb   = (unsigned short*)take(4096ull*256*2);   // per-batch [l][o]
  float* G             = (float*)take(4096ull*4096*4);           // per-batch
  char* unionB         = take(4096ull*4096*2);                   // 32MB union
  unsigned short* xn   = (unsigned short*)unionB;
  unsigned short* sn   = (unsigned short*)(unionB + 4096ull*1536*2);
  unsigned short* fst  = (unsigned short*)(unionB + 2ull*4096*1536*2);
  unsigned short* P    = (unsigned short*)unionB;                // after xn/sn/fst dead
  float* partF          = G;                   // f32 partials overlay dead G
  unsigned short* partH = (unsigned short*)G;  // bf16 partials overlay dead G
  const size_t zS1 = 4096ull*256;   // 1M elems (th/ph/y/g slices)
  const size_t zSW = 512ull*4096;   // 2M elems (W slices)

  detect_prep<<<1, 256, 0, stream>>>(content, theta_b, phi_b, g_b, W_b, scale,
                                     flag, scale_c, tb_c, pb_c, gb_c, wb_c);
  conv_weights<<<dim3(512,4), 256, 0, stream>>>(theta_w, phi_w, g_w, W_w, flag,
                                                wdup, gwc, wwc);
  stats_kernel<<<1024, 256, 0, stream>>>(content, flag, statsC);
  stats_kernel<<<1024, 256, 0, stream>>>(style,   flag, statsS);

  for (int b = 0; b < 2; ++b){
    dim3 ntg(64, 8, 1);
    norm_transpose<true ><<<ntg, 256, 0, stream>>>(content, statsC, xn, flag, b);
    norm_transpose<true ><<<ntg, 256, 0, stream>>>(style,   statsS, sn, flag, b);
    norm_transpose<false><<<ntg, 256, 0, stream>>>(fusion,  nullptr, fst, flag, b);

    // theta: (4096x256) = xn(4096x1536)*wdup_t(256x1536)^T, split-K 4x384 (f32)
    gemm_bt<OUT_PART, BIAS_NONE><<<dim3(2,32,4), 256, 0, stream>>>(
        xn, 1536, wdup, 1536, 384, partF, 256, nullptr, 0, 0, nullptr, 0, zS1);
    reduce_part<4, OUT_SPLIT3, BIAS_COL, 8, false><<<4096, 256, 0, stream>>>(
        partF, zS1, tb_c, th, 768, 256, 512, nullptr, 0);
    // phi -> ph [hi|lo|hi]
    gemm_bt<OUT_PART, BIAS_NONE><<<dim3(2,32,4), 256, 0, stream>>>(
        sn, 1536, wdup + 256*1536, 1536, 384, partF, 256, nullptr, 0, 0, nullptr, 0, zS1);
    reduce_part<4, OUT_SPLIT3, BIAS_COL, 8, false><<<4096, 256, 0, stream>>>(
        partF, zS1, pb_c, ph, 768, 512, 256, nullptr, 0);
    // g: (256x4096) = gwc(256x512) * fst(4096x512)^T, split-K 4x128 (bf16)
    gemm_bt<OUT_PARTH, BIAS_NONE><<<dim3(32,2,4), 256, 0, stream>>>(
        gwc, 512, fst, 512, 128, partH, 4096, nullptr, 0, 0, nullptr, 0, zS1);
    reduce_part<4, OUT_BF16, BIAS_ROW, 12, true><<<4096, 256, 0, stream>>>(
        partH, zS1, gb_c, gs, 4096, 0, 0, nullptr, 0);
    // G = th * ph^T (f32), K=768 compensated product
    gemm_bt<OUT_F32, BIAS_NONE><<<dim3(32,32), 256, 0, stream>>>(
        th, 768, ph, 768, 768, G, 4096, nullptr, 0, 0, nullptr, 0, 0);
    // f-assembly + rowwise softmax -> P (bf16); P overlays dead xn/sn/fst
    softmax_rows<<<4096, 256, 0, stream>>>(G, scale_c, P);
    // y = P * gs^T : (4096x256), split-K 8x512, bf16 partials (overlay dead G)
    gemm_bt<OUT_PARTH, BIAS_NONE><<<dim3(2,32,8), 256, 0, stream>>>(
        P, 4096, gs, 4096, 512, partH, 256, nullptr, 0, 0, nullptr, 0, zS1);
    reduce_part<8, OUT_BF16, BIAS_NONE, 8, true><<<4096, 256, 0, stream>>>(
        partH, zS1, nullptr, yb, 256, 0, 0, nullptr, 0);
    // out = wwc(512x256) * yb(4096x256)^T + W_b, split-K 2x128 (f32 partials
    // overlay dead G); reduce applies row bias + flag dtype
    gemm_bt<OUT_PART, BIAS_NONE><<<dim3(32,4,2), 256, 0, stream>>>(
        wwc, 256, yb, 256, 128, partF, 4096, nullptr, 0, 0, nullptr, 0, zSW);
    reduce_part<2, OUT_FLAG, BIAS_ROW, 12, false><<<8192, 256, 0, stream>>>(
        partF, zSW, wb_c, d_out, 4096, 0, 0, flag, (size_t)b*512*4096);
  }
}

// Round 7
// 473.149 us; speedup vs baseline: 1.0749x; 1.0454x over previous
//
#include <hip/hip_runtime.h>
#include <stdint.h>

typedef __attribute__((ext_vector_type(8))) __bf16 bf16x8;
typedef __attribute__((ext_vector_type(4))) float f32x4;
typedef __attribute__((ext_vector_type(4))) unsigned int uint4v;

__device__ __forceinline__ float bf2f(unsigned short u){
  unsigned int x = ((unsigned int)u) << 16;
  return __builtin_bit_cast(float, x);
}
__device__ __forceinline__ unsigned short f2bf(float f){
  unsigned int x = __builtin_bit_cast(unsigned int, f);
  x += 0x7FFFu + ((x >> 16) & 1u);
  return (unsigned short)(x >> 16);
}

#define OUT_F32 0
#define OUT_BF16 1
#define OUT_SPLIT3 2
#define OUT_FLAG 3
#define OUT_PART 4
#define OUT_PARTH 5
#define BIAS_NONE 0
#define BIAS_ROW 1
#define BIAS_COL 2

// C(MxN) = A(MxK) * Bt(NxK)^T ; M,N multiples of 128, kchunk multiple of 32.
// blockIdx.z selects K-slice; OUT_PART(f32)/OUT_PARTH(bf16) write partials at
// z*zStride. A, Bt bf16 K-contiguous. 128x128 tile, 4 waves, 16x16x32 MFMA.
// Register staging + DOUBLE-BUFFERED LDS: one barrier per K-step.
//   iter kt: ds_write buf[kt&1] (consumes prefetched regs), barrier,
//            issue global loads kt+1, ds_read buf[kt&1] + MFMA.
// (async global_load_lds measured SLOWER: R5 52us vs 45.5us reg-staged.)
// LDS: row r at byte r*64; 16B-chunk p of row r holds k-chunk (p ^ ((r>>1)&3)).
template<int OM, int BM>
__global__ __launch_bounds__(256)
void gemm_bt(const unsigned short* __restrict__ A, int lda,
             const unsigned short* __restrict__ Bt, int ldb,
             int kchunk, void* __restrict__ Out, int ldo,
             const float* __restrict__ bias,
             int dupOff, int loOff,
             const unsigned int* __restrict__ flagPtr, size_t outOff,
             size_t zStride)
{
  __shared__ uint4v AsmBuf[1024];   // 2 x 8KB
  __shared__ uint4v BsmBuf[1024];
  char* Asm = (char*)AsmBuf;
  char* Bsm = (char*)BsmBuf;

  const unsigned int fl = (OM == OUT_FLAG) ? flagPtr[0] : 0u;

  const int tid  = threadIdx.x;
  const int lane = tid & 63;
  const int wave = tid >> 6;
  const int wy = wave >> 1, wx = wave & 1;
  const int lm = lane & 15, quad = lane >> 4;
  const int tileM = blockIdx.y * 128;
  const int tileN = blockIdx.x * 128;
  const int z = blockIdx.z;

  A  += (size_t)z * kchunk;
  Bt += (size_t)z * kchunk;

  const int sr0 = tid >> 2, sc0 = tid & 3;
  const int sr1 = sr0 + 64;
  const size_t gA0 = (size_t)(tileM + sr0)*lda + ((sc0 ^ ((sr0 >> 1) & 3)) << 3);
  const size_t gA1 = (size_t)(tileM + sr1)*lda + ((sc0 ^ ((sr1 >> 1) & 3)) << 3);
  const size_t gB0 = (size_t)(tileN + sr0)*ldb + ((sc0 ^ ((sr0 >> 1) & 3)) << 3);
  const size_t gB1 = (size_t)(tileN + sr1)*ldb + ((sc0 ^ ((sr1 >> 1) & 3)) << 3);
  const int lOff0 = sr0*64 + sc0*16;
  const int lOff1 = sr1*64 + sc0*16;

  int aOff[4], bOff[4];
#pragma unroll
  for (int t = 0; t < 4; ++t){
    int ra = wy*64 + t*16 + lm;
    aOff[t] = ra*64 + ((quad ^ ((ra >> 1) & 3)) << 4);
    int rb = wx*64 + t*16 + lm;
    bOff[t] = rb*64 + ((quad ^ ((rb >> 1) & 3)) << 4);
  }

  f32x4 acc[4][4] = {};

  const int ksteps = kchunk >> 5;
  // prologue: prefetch k-step 0 into registers
  uint4v a0v = *(const uint4v*)(A + gA0);
  uint4v a1v = *(const uint4v*)(A + gA1);
  uint4v b0v = *(const uint4v*)(Bt + gB0);
  uint4v b1v = *(const uint4v*)(Bt + gB1);

  for (int kt = 0; kt < ksteps; ++kt){
    char* As = Asm + (kt & 1)*8192;
    char* Bs = Bsm + (kt & 1)*8192;
    *(uint4v*)(As + lOff0) = a0v;
    *(uint4v*)(As + lOff1) = a1v;
    *(uint4v*)(Bs + lOff0) = b0v;
    *(uint4v*)(Bs + lOff1) = b1v;
    __syncthreads();
    if (kt + 1 < ksteps){
      const unsigned short* Ak = A + (kt + 1)*32;
      const unsigned short* Bk = Bt + (kt + 1)*32;
      a0v = *(const uint4v*)(Ak + gA0);
      a1v = *(const uint4v*)(Ak + gA1);
      b0v = *(const uint4v*)(Bk + gB0);
      b1v = *(const uint4v*)(Bk + gB1);
    }
    bf16x8 af[4], bfr[4];
#pragma unroll
    for (int t = 0; t < 4; ++t){
      af[t]  = __builtin_bit_cast(bf16x8, *(const uint4v*)(As + aOff[t]));
      bfr[t] = __builtin_bit_cast(bf16x8, *(const uint4v*)(Bs + bOff[t]));
    }
#pragma unroll
    for (int tm = 0; tm < 4; ++tm)
#pragma unroll
      for (int tn = 0; tn < 4; ++tn)
        acc[tm][tn] = __builtin_amdgcn_mfma_f32_16x16x32_bf16(af[tm], bfr[tn], acc[tm][tn], 0, 0, 0);
  }

  // D row = quad*4 + reg, col = lane&15
#pragma unroll
  for (int tm = 0; tm < 4; ++tm){
    const int rowb = tileM + wy*64 + tm*16 + quad*4;
#pragma unroll
    for (int tn = 0; tn < 4; ++tn){
      const int col = tileN + wx*64 + tn*16 + lm;
      float bcv = 0.f;
      if (BM == BIAS_COL) bcv = bias[col];
#pragma unroll
      for (int r = 0; r < 4; ++r){
        float v = acc[tm][tn][r];
        const int row = rowb + r;
        if (BM == BIAS_ROW) v += bias[row];
        if (BM == BIAS_COL) v += bcv;
        const size_t idx = (size_t)row*ldo + col;
        if (OM == OUT_F32){
          ((float*)Out)[idx] = v;
        } else if (OM == OUT_BF16){
          ((unsigned short*)Out)[idx] = f2bf(v);
        } else if (OM == OUT_SPLIT3){
          unsigned short hi = f2bf(v);
          unsigned short lo = f2bf(v - bf2f(hi));
          unsigned short* O = (unsigned short*)Out;
          O[idx] = hi; O[idx + dupOff] = hi; O[idx + loOff] = lo;
        } else if (OM == OUT_PART){
          ((float*)Out)[(size_t)z*zStride + idx] = v;
        } else if (OM == OUT_PARTH){
          ((unsigned short*)Out)[(size_t)z*zStride + idx] = f2bf(v);
        } else { // OUT_FLAG
          if (fl) ((float*)Out)[outOff + idx] = v;
          else    ((unsigned short*)Out)[outOff + idx] = f2bf(v);
        }
      }
    }
  }
}

// sum S partial slices (flat [S][rows*cols]) -> epilogue.
// CSH = log2(cols). HALFP: bf16 partials. i = bid*256+tid; row=i>>CSH, col=i&mask.
template<int S, int OM, int BM, int CSH, bool HALFP>
__global__ __launch_bounds__(256)
void reduce_part(const void* __restrict__ part, size_t zStride,
                 const float* __restrict__ bias,
                 void* __restrict__ Out, int ldo,
                 int dupOff, int loOff,
                 const unsigned int* __restrict__ flagPtr, size_t outOff)
{
  const size_t i = (size_t)blockIdx.x*256 + threadIdx.x;
  const int row = (int)(i >> CSH);
  const int col = (int)(i & ((1u << CSH) - 1u));
  float v = 0.f;
#pragma unroll
  for (int s = 0; s < S; ++s){
    if (HALFP) v += bf2f(((const unsigned short*)part)[(size_t)s*zStride + i]);
    else       v += ((const float*)part)[(size_t)s*zStride + i];
  }
  if (BM == BIAS_ROW) v += bias[row];
  if (BM == BIAS_COL) v += bias[col];
  const size_t o = (size_t)row*ldo + col;
  if (OM == OUT_SPLIT3){
    unsigned short hi = f2bf(v);
    unsigned short lo = f2bf(v - bf2f(hi));
    unsigned short* O = (unsigned short*)Out;
    O[o] = hi; O[o + dupOff] = hi; O[o + loOff] = lo;
  } else if (OM == OUT_BF16){
    ((unsigned short*)Out)[o] = f2bf(v);
  } else { // OUT_FLAG
    if (flagPtr[0]) ((float*)Out)[outOff + o] = v;
    else            ((unsigned short*)Out)[outOff + o] = f2bf(v);
  }
}

// dtype vote + scalar/bias canonicalization (f32 canon)
__global__ __launch_bounds__(256)
void detect_prep(const void* __restrict__ content,
                 const void* tb, const void* pb, const void* gb, const void* wb,
                 const void* sc,
                 unsigned int* __restrict__ flag, float* __restrict__ scale_c,
                 float* tb_c, float* pb_c, float* gb_c, float* wb_c)
{
  __shared__ int cnt;
  __shared__ unsigned int flg;
  const int tid = threadIdx.x;
  if (tid == 0) cnt = 0;
  __syncthreads();
  unsigned int w = ((const unsigned int*)content)[tid];
  int e = (w >> 23) & 0xFF;
  if (e >= 0x70 && e <= 0x8F) atomicAdd(&cnt, 1);
  __syncthreads();
  if (tid == 0){ flg = (cnt >= 128) ? 1u : 0u; flag[0] = flg; }
  __syncthreads();
  const unsigned int f = flg;
  auto rd = [&](const void* p, int i)->float{
    return f ? ((const float*)p)[i] : bf2f(((const unsigned short*)p)[i]);
  };
  if (tid < 9) scale_c[tid] = rd(sc, tid);
  tb_c[tid] = rd(tb, tid);
  pb_c[tid] = rd(pb, tid);
  gb_c[tid] = rd(gb, tid);
  wb_c[tid] = rd(wb, tid);
  wb_c[tid + 256] = rd(wb, tid + 256);
}

// canonicalize weights: theta/phi -> wdup rows [whi(512)|wlo(512)|whi(512)],
// g_w -> gwc bf16, W_w -> wwc bf16
__global__ __launch_bounds__(256)
void conv_weights(const void* tw, const void* pw, const void* gw, const void* www,
                  const unsigned int* __restrict__ flagPtr,
                  unsigned short* __restrict__ wdup,
                  unsigned short* __restrict__ gwc,
                  unsigned short* __restrict__ wwc)
{
  const unsigned int fl = flagPtr[0];
  const int sec = blockIdx.y;
  const int idx = blockIdx.x*256 + threadIdx.x;
  auto rd = [&](const void* p, int i)->float{
    return fl ? ((const float*)p)[i] : bf2f(((const unsigned short*)p)[i]);
  };
  if (sec < 2){
    const void* w = sec ? pw : tw;
    const int o = idx >> 9, c = idx & 511;
    float v = rd(w, o*512 + c);
    unsigned short hi = f2bf(v);
    unsigned short lo = f2bf(v - bf2f(hi));
    unsigned short* base = wdup + (size_t)sec*256*1536 + o*1536;
    base[c] = hi; base[512 + c] = lo; base[1024 + c] = hi;
  } else if (sec == 2){
    const int o = idx >> 9, c = idx & 511;
    gwc[o*512 + c] = f2bf(rd(gw, o*512 + c));
  } else {
    const int o = idx >> 8, c = idx & 255;
    wwc[o*256 + c] = f2bf(rd(www, o*256 + c));
  }
}

// per-(b,c) mean / invstd over 4096 spatial elems (unbiased var)
__global__ __launch_bounds__(256)
void stats_kernel(const void* __restrict__ X, const unsigned int* __restrict__ flagPtr,
                  float* __restrict__ stats)
{
  const unsigned int fl = flagPtr[0];
  const int bc = blockIdx.x;
  const int tid = threadIdx.x;
  float s = 0.f, q = 0.f;
  if (fl){
    const f32x4* row = (const f32x4*)((const float*)X + (size_t)bc*4096);
#pragma unroll
    for (int i = 0; i < 4; ++i){
      f32x4 v = row[tid + i*256];
#pragma unroll
      for (int j = 0; j < 4; ++j){ s += v[j]; q += v[j]*v[j]; }
    }
  } else {
    const uint4v* row = (const uint4v*)((const unsigned short*)X + (size_t)bc*4096);
#pragma unroll
    for (int i = 0; i < 2; ++i){
      uint4v u = row[tid + i*256];
#pragma unroll
      for (int j = 0; j < 4; ++j){
        float a = bf2f((unsigned short)(u[j] & 0xffffu));
        float b = bf2f((unsigned short)(u[j] >> 16));
        s += a + b; q += a*a + b*b;
      }
    }
  }
#pragma unroll
  for (int off = 32; off > 0; off >>= 1){
    s += __shfl_down(s, off);
    q += __shfl_down(q, off);
  }
  __shared__ float rs[4], rq[4];
  if ((tid & 63) == 0){ rs[tid >> 6] = s; rq[tid >> 6] = q; }
  __syncthreads();
  if (tid == 0){
    s = rs[0] + rs[1] + rs[2] + rs[3];
    q = rq[0] + rq[1] + rq[2] + rq[3];
    float mean = s * (1.0f/4096.0f);
    float var  = (q - 4096.0f*mean*mean) * (1.0f/4095.0f);
    stats[bc*2 + 0] = mean;
    stats[bc*2 + 1] = 1.0f / sqrtf(var + 1e-5f);
  }
}

// (c,l) -> (l,c) transpose for batch b.
// SPLIT: normalize, write rows [xhi(512)|xhi(512)|xlo(512)] (ldo=1536)
// else: plain bf16 (ldo=512)
template<bool SPLIT>
__global__ __launch_bounds__(256)
void norm_transpose(const void* __restrict__ X, const float* __restrict__ stats,
                    unsigned short* __restrict__ Out,
                    const unsigned int* __restrict__ flagPtr, int b)
{
  __shared__ float tile[64][65];
  const unsigned int fl = flagPtr[0];
  const int l0 = blockIdx.x * 64;
  const int c0 = blockIdx.y * 64;
  const int tid = threadIdx.x;
  const int tx = tid & 63, ty = tid >> 6;

#pragma unroll
  for (int p = 0; p < 16; ++p){
    const int cc = ty + p*4;
    const size_t src = ((size_t)b*512 + c0 + cc)*4096 + l0 + tx;
    tile[cc][tx] = fl ? ((const float*)X)[src]
                      : bf2f(((const unsigned short*)X)[src]);
  }
  __syncthreads();
  float mean = 0.f, inv = 1.f;
  if (SPLIT){
    mean = stats[(b*512 + c0 + tx)*2 + 0];
    inv  = stats[(b*512 + c0 + tx)*2 + 1];
  }
#pragma unroll
  for (int p = 0; p < 16; ++p){
    const int lj = ty + p*4;
    if (SPLIT){
      const float v = (tile[tx][lj] - mean) * inv;
      const size_t o = (size_t)(l0 + lj)*1536 + c0 + tx;
      const unsigned short hi = f2bf(v);
      Out[o] = hi;
      Out[o + 512] = hi;
      Out[o + 1024] = f2bf(v - bf2f(hi));
    } else {
      const size_t o = (size_t)(l0 + lj)*512 + c0 + tx;
      Out[o] = f2bf(tile[tx][lj]);
    }
  }
}

// f[l,m] = sum_{di,dj} s^2 * G[refl_l, refl_m]; rowwise softmax; write P bf16
__global__ __launch_bounds__(256)
void softmax_rows(const float* __restrict__ G, const float* __restrict__ scale_c,
                  unsigned short* __restrict__ P)
{
  const int l = blockIdx.x;
  const int yy = l >> 6, xx = l & 63;
  const int tid = threadIdx.x;

  float s2[9];
  const float* rowp[9];
#pragma unroll
  for (int di = 0; di < 3; ++di){
    int ry = yy + di - 1; ry = ry < 0 ? 1 : (ry > 63 ? 62 : ry);
#pragma unroll
    for (int dj = 0; dj < 3; ++dj){
      int rx = xx + dj - 1; rx = rx < 0 ? 1 : (rx > 63 ? 62 : rx);
      const int k = di*3 + dj;
      const float s = scale_c[k];
      s2[k] = s*s;
      rowp[k] = G + (size_t)(ry*64 + rx)*4096;
    }
  }

  float fv[16];
  float mx = -3.0e38f;
#pragma unroll
  for (int i = 0; i < 16; ++i){
    const int m = tid + i*256;
    const int my = m >> 6, mxo = m & 63;
    int cy[3], cx[3];
#pragma unroll
    for (int d = 0; d < 3; ++d){
      int t0 = my + d - 1;  cy[d] = (t0 < 0 ? 1 : (t0 > 63 ? 62 : t0))*64;
      int t1 = mxo + d - 1; cx[d] = (t1 < 0 ? 1 : (t1 > 63 ? 62 : t1));
    }
    float v = 0.f;
#pragma unroll
    for (int di = 0; di < 3; ++di)
#pragma unroll
      for (int dj = 0; dj < 3; ++dj)
        v = fmaf(s2[di*3+dj], rowp[di*3+dj][cy[di] + cx[dj]], v);
    fv[i] = v;
    mx = fmaxf(mx, v);
  }

  __shared__ float redA[4], redB[4];
#pragma unroll
  for (int off = 32; off > 0; off >>= 1) mx = fmaxf(mx, __shfl_down(mx, off));
  if ((tid & 63) == 0) redA[tid >> 6] = mx;
  __syncthreads();
  mx = fmaxf(fmaxf(redA[0], redA[1]), fmaxf(redA[2], redA[3]));

  float sum = 0.f;
#pragma unroll
  for (int i = 0; i < 16; ++i){ fv[i] = __expf(fv[i] - mx); sum += fv[i]; }
#pragma unroll
  for (int off = 32; off > 0; off >>= 1) sum += __shfl_down(sum, off);
  if ((tid & 63) == 0) redB[tid >> 6] = sum;
  __syncthreads();
  sum = redB[0] + redB[1] + redB[2] + redB[3];
  const float inv = 1.0f / sum;

  unsigned short* Prow = P + (size_t)l*4096;
#pragma unroll
  for (int i = 0; i < 16; ++i) Prow[tid + i*256] = f2bf(fv[i]*inv);
}

extern "C" void kernel_launch(void* const* d_in, const int* in_sizes, int n_in,
                              void* d_out, int out_size, void* d_ws, size_t ws_size,
                              hipStream_t stream)
{
  const void* content = d_in[0];
  const void* style   = d_in[1];
  const void* fusion  = d_in[2];
  const void* theta_w = d_in[3];
  const void* theta_b = d_in[4];
  const void* phi_w   = d_in[5];
  const void* phi_b   = d_in[6];
  const void* g_w     = d_in[7];
  const void* g_b     = d_in[8];
  const void* W_w     = d_in[9];
  const void* W_b     = d_in[10];
  const void* scale   = d_in[11];

  char* ws = (char*)d_ws;
  size_t off = 0;
  auto take = [&](size_t bytes)->char*{
    char* p = ws + off; off += (bytes + 255) & ~(size_t)255; return p;
  };

  unsigned int* flag  = (unsigned int*)take(256);
  float* scale_c      = (float*)take(256);
  float* tb_c         = (float*)take(1024);
  float* pb_c         = (float*)take(1024);
  float* gb_c         = (float*)take(1024);
  float* wb_c         = (float*)take(2048);
  float* statsC       = (float*)take(1024ull*2*4);
  float* statsS       = (float*)take(1024ull*2*4);
  unsigned short* wdup = (unsigned short*)take(2ull*256*1536*2); // theta|phi [hi|lo|hi]
  unsigned short* gwc  = (unsigned short*)take(256ull*512*2);
  unsigned short* wwc  = (unsigned short*)take(512ull*256*2);
  unsigned short* th   = (unsigned short*)take(4096ull*768*2);   // per-batch [hi|hi|lo]
  unsigned short* ph   = (unsigned short*)take(4096ull*768*2);   // per-batch [hi|lo|hi]
  unsigned short* gs   = (unsigned short*)take(256ull*4096*2);   // per-batch [o][m]
  unsigned short* yb   = (unsigned short*)take(4096ull*256*2);   // per-batch [l][o]
  float* G             = (float*)take(4096ull*4096*4);           // per-batch
  char* unionB         = take(4096ull*4096*2);                   // 32MB union
  unsigned short* xn   = (unsigned short*)unionB;
  unsigned short* sn   = (unsigned short*)(unionB + 4096ull*1536*2);
  unsigned short* fst  = (unsigned short*)(unionB + 2ull*4096*1536*2);
  unsigned short* P    = (unsigned short*)unionB;                // after xn/sn/fst dead
  float* partF          = G;                   // f32 partials overlay dead G
  unsigned short* partH = (unsigned short*)G;  // bf16 partials overlay dead G
  const size_t zS1 = 4096ull*256;   // 1M elems (th/ph/y/g slices)
  const size_t zSW = 512ull*4096;   // 2M elems (W slices)

  detect_prep<<<1, 256, 0, stream>>>(content, theta_b, phi_b, g_b, W_b, scale,
                                     flag, scale_c, tb_c, pb_c, gb_c, wb_c);
  conv_weights<<<dim3(512,4), 256, 0, stream>>>(theta_w, phi_w, g_w, W_w, flag,
                                                wdup, gwc, wwc);
  stats_kernel<<<1024, 256, 0, stream>>>(content, flag, statsC);
  stats_kernel<<<1024, 256, 0, stream>>>(style,   flag, statsS);

  for (int b = 0; b < 2; ++b){
    dim3 ntg(64, 8, 1);
    norm_transpose<true ><<<ntg, 256, 0, stream>>>(content, statsC, xn, flag, b);
    norm_transpose<true ><<<ntg, 256, 0, stream>>>(style,   statsS, sn, flag, b);
    norm_transpose<false><<<ntg, 256, 0, stream>>>(fusion,  nullptr, fst, flag, b);

    // theta: (4096x256) = xn(4096x1536)*wdup_t(256x1536)^T, split-K 4x384 (f32)
    gemm_bt<OUT_PART, BIAS_NONE><<<dim3(2,32,4), 256, 0, stream>>>(
        xn, 1536, wdup, 1536, 384, partF, 256, nullptr, 0, 0, nullptr, 0, zS1);
    reduce_part<4, OUT_SPLIT3, BIAS_COL, 8, false><<<4096, 256, 0, stream>>>(
        partF, zS1, tb_c, th, 768, 256, 512, nullptr, 0);
    // phi -> ph [hi|lo|hi]
    gemm_bt<OUT_PART, BIAS_NONE><<<dim3(2,32,4), 256, 0, stream>>>(
        sn, 1536, wdup + 256*1536, 1536, 384, partF, 256, nullptr, 0, 0, nullptr, 0, zS1);
    reduce_part<4, OUT_SPLIT3, BIAS_COL, 8, false><<<4096, 256, 0, stream>>>(
        partF, zS1, pb_c, ph, 768, 512, 256, nullptr, 0);
    // g: (256x4096) = gwc(256x512) * fst(4096x512)^T, split-K 4x128 (bf16)
    gemm_bt<OUT_PARTH, BIAS_NONE><<<dim3(32,2,4), 256, 0, stream>>>(
        gwc, 512, fst, 512, 128, partH, 4096, nullptr, 0, 0, nullptr, 0, zS1);
    reduce_part<4, OUT_BF16, BIAS_ROW, 12, true><<<4096, 256, 0, stream>>>(
        partH, zS1, gb_c, gs, 4096, 0, 0, nullptr, 0);
    // G = th * ph^T (f32), K=768 compensated product
    gemm_bt<OUT_F32, BIAS_NONE><<<dim3(32,32), 256, 0, stream>>>(
        th, 768, ph, 768, 768, G, 4096, nullptr, 0, 0, nullptr, 0, 0);
    // f-assembly + rowwise softmax -> P (bf16); P overlays dead xn/sn/fst
    softmax_rows<<<4096, 256, 0, stream>>>(G, scale_c, P);
    // y = P * gs^T : (4096x256), split-K 8x512, bf16 partials (overlay dead G)
    gemm_bt<OUT_PARTH, BIAS_NONE><<<dim3(2,32,8), 256, 0, stream>>>(
        P, 4096, gs, 4096, 512, partH, 256, nullptr, 0, 0, nullptr, 0, zS1);
    reduce_part<8, OUT_BF16, BIAS_NONE, 8, true><<<4096, 256, 0, stream>>>(
        partH, zS1, nullptr, yb, 256, 0, 0, nullptr, 0);
    // out = wwc(512x256) * yb(4096x256)^T + W_b, split-K 2x128 (f32 partials
    // overlay dead G); reduce applies row bias + flag dtype
    gemm_bt<OUT_PART, BIAS_NONE><<<dim3(32,4,2), 256, 0, stream>>>(
        wwc, 256, yb, 256, 128, partF, 4096, nullptr, 0, 0, nullptr, 0, zSW);
    reduce_part<2, OUT_FLAG, BIAS_ROW, 12, false><<<8192, 256, 0, stream>>>(
        partF, zSW, wb_c, d_out, 4096, 0, 0, flag, (size_t)b*512*4096);
  }
}